// Round 6
// baseline (321.020 us; speedup 1.0000x reference)
//
#include <hip/hip_runtime.h>

typedef unsigned short ushort_t;
typedef unsigned int uint32;
typedef __attribute__((ext_vector_type(8))) short short8;
typedef __attribute__((ext_vector_type(4))) float f32x4;
typedef __attribute__((ext_vector_type(2))) uint32 u32x2;

#define LDS_LOAD16(gptr, lptr)                                                             \
  __builtin_amdgcn_global_load_lds((const __attribute__((address_space(1))) uint32*)(gptr),\
                                   (__attribute__((address_space(3))) uint32*)(lptr),      \
                                   16, 0, 0)

__device__ __forceinline__ ushort_t f2b(float f) {
  uint32 u = __builtin_bit_cast(uint32, f);
  u += 0x7fffu + ((u >> 16) & 1u);   // RNE
  return (ushort_t)(u >> 16);
}
__device__ __forceinline__ uint32 pk2(float a, float b) {
  return (uint32)f2b(a) | ((uint32)f2b(b) << 16);
}

constexpr size_t E = (size_t)2048 * 2048;

// ---------------- fused fp32 -> bf16 convert (all 5 tensors) ----------------
__global__ __launch_bounds__(256) void k_cvt5(const float* __restrict__ a0, const float* __restrict__ a1,
                                              const float* __restrict__ a2, const float* __restrict__ a3,
                                              const float* __restrict__ a4, ushort_t* __restrict__ out) {
  const float* srcs[5] = {a0, a1, a2, a3, a4};
  const float* s = srcs[blockIdx.y];
  size_t i = ((size_t)blockIdx.x * 256 + threadIdx.x) * 4;
  float4 v = *(const float4*)(s + i);
  ushort4 o;
  o.x = f2b(v.x); o.y = f2b(v.y); o.z = f2b(v.z); o.w = f2b(v.w);
  *(ushort4*)(out + (size_t)blockIdx.y * E + i) = o;
}

// ===================== GEMM: A via 3-buffer gl_lds rotation, B direct global->reg =====================
// LDS-traffic model (R5 counters): old structure moved 12KB LDS/body/wave for 16 MFMAs ->
// LDS-BW-bound (~30us floor). B-frags have a clean per-lane global pattern and are XCD-L2
// resident (col-block => fixed x%8 => same XCD), so B bypasses LDS via a 2-deep register
// double-buffer; only A stays in LDS. Halves LDS traffic, LDS 48K->24K.
// vmcnt discipline (mixed stream, memory-clobber fences pin each body's 6 VMEM =
// 4 B-loads + 2 A-stages between fences): uniform vmcnt(6) at body end == "everything
// older than this body retired" => A(t+1) landed; tail vmcnt(4). Compiler-inserted waits
// for b-regs remain correct (our asm waits only reduce outstanding counts).
#define SWZ3(r) (((r) >> 1) & 3)

#define STG_A(dA, ktile)                                                        \
  do {                                                                          \
    const int koff_ = (ktile) * 32;                                             \
    _Pragma("unroll") for (int j2_ = 0; j2_ < 2; ++j2_) {                       \
      int c_ = tid + 256 * j2_;                                                 \
      int r_ = c_ >> 2, p_ = c_ & 3;                                            \
      int sc_ = (p_ ^ SWZ3(r_)) * 8;                                            \
      LDS_LOAD16(Asrc + (row0 + r_) * 2048 + koff_ + sc_, &(dA)[c_ * 8]);       \
    }                                                                           \
  } while (0)

#define LOADB(dst, KT)                                                          \
  _Pragma("unroll") for (int j_ = 0; j_ < 4; ++j_)                              \
    (dst)[j_] = *(const short8*)(Bpt[j_] + (size_t)(KT) * 32);

#define GFRAGS(ASBUF, BARR)                                                     \
  do {                                                                          \
    short8 a_[4];                                                               \
    _Pragma("unroll") for (int i_ = 0; i_ < 4; ++i_) {                          \
      int ra_ = wm * 64 + i_ * 16 + l16;                                        \
      a_[i_] = *(const short8*)&(ASBUF)[(ra_ * 4 + (quad ^ SWZ3(ra_))) * 8];    \
    }                                                                           \
    _Pragma("unroll") for (int i_ = 0; i_ < 4; ++i_)                            \
      _Pragma("unroll") for (int j_ = 0; j_ < 4; ++j_)                          \
        acc[i_][j_] = __builtin_amdgcn_mfma_f32_16x16x32_bf16(a_[i_], (BARR)[j_], acc[i_][j_], 0, 0, 0); \
  } while (0)

#define GBODY(T, CUR, STG, BC, BN, SEN, BEN, VM)                                \
  do {                                                                          \
    if (BEN) { LOADB(BN, (T) + 1); }                                            \
    if (SEN) STG_A(As[STG], (T) + 2);                                           \
    GFRAGS(As[CUR], BC);                                                        \
    asm volatile("s_waitcnt " VM ::: "memory");                                 \
    __builtin_amdgcn_s_barrier();                                               \
  } while (0)

#define GPROLOGUE()                                                             \
  do {                                                                          \
    LOADB(b0, 0);                                                               \
    STG_A(As[0], 0);                                                            \
    asm volatile("" ::: "memory");                                              \
    STG_A(As[1], 1);                                                            \
    asm volatile("s_waitcnt vmcnt(2)" ::: "memory");                            \
    __builtin_amdgcn_s_barrier();                                               \
  } while (0)

// ---------------- fused QKV GEMM-BT, fused RoPE epilogue ----------------
// z=0 -> Qm (rope + 1/sqrt(dh) scale), z=1 -> Km (rope), z=2 -> Vt (transposed write)
__global__ __launch_bounds__(256, 3) void k_gemm_qkv(const ushort_t* __restrict__ A,
                                                     const ushort_t* __restrict__ B0,
                                                     const ushort_t* __restrict__ B1,
                                                     const ushort_t* __restrict__ B2,
                                                     ushort_t* __restrict__ Qm,
                                                     ushort_t* __restrict__ Km,
                                                     ushort_t* __restrict__ Vt,
                                                     const int* __restrict__ pos) {
  __shared__ ushort_t As[3][128 * 32];
  const int tid = threadIdx.x;
  const int lane = tid & 63, wave = tid >> 6;
  const int quad = lane >> 4, l16 = lane & 15;
  const int wm = wave >> 1, wn = wave & 1;
  const int z = blockIdx.z;
  const ushort_t* Bp = (z == 0) ? B0 : (z == 1) ? B1 : B2;
  const size_t row0 = (size_t)blockIdx.y * 128, col0 = (size_t)blockIdx.x * 128;
  const ushort_t* Asrc = A;

  int g[4];
#pragma unroll
  for (int j = 0; j < 4; ++j) g[j] = (j & 1) + ((j >> 1) << 2) + wn * 2;  // {0,1,4,5}/{2,3,6,7}

  const ushort_t* Bpt[4];
#pragma unroll
  for (int j = 0; j < 4; ++j) Bpt[j] = Bp + (size_t)(col0 + g[j] * 16 + l16) * 2048 + quad * 8;

  f32x4 zero = {0.f, 0.f, 0.f, 0.f};
  f32x4 acc[4][4];
#pragma unroll
  for (int i = 0; i < 4; ++i)
#pragma unroll
    for (int j = 0; j < 4; ++j) acc[i][j] = zero;

  short8 b0[4], b1[4];
  GPROLOGUE();

  for (int tt = 0; tt < 60; tt += 6) {
    GBODY(tt + 0, 0, 2, b0, b1, 1, 1, "vmcnt(6)");
    GBODY(tt + 1, 1, 0, b1, b0, 1, 1, "vmcnt(6)");
    GBODY(tt + 2, 2, 1, b0, b1, 1, 1, "vmcnt(6)");
    GBODY(tt + 3, 0, 2, b1, b0, 1, 1, "vmcnt(6)");
    GBODY(tt + 4, 1, 0, b0, b1, 1, 1, "vmcnt(6)");
    GBODY(tt + 5, 2, 1, b1, b0, 1, 1, "vmcnt(6)");
  }
  GBODY(60, 0, 2, b0, b1, 1, 1, "vmcnt(6)");
  GBODY(61, 1, 0, b1, b0, 1, 1, "vmcnt(6)");   // stages A(63) into As[0], loads B(62)
  GBODY(62, 2, 0, b0, b1, 0, 1, "vmcnt(4)");   // loads B(63); retires A(63)
  GFRAGS(As[0], b1);                           // body 63

  if (z < 2) {
    ushort_t* C = z ? Km : Qm;
    const float mul = z ? 1.0f : 0.08838834764831845f;  // fold 1/sqrt(128) into Q
#pragma unroll
    for (int i = 0; i < 4; ++i)
#pragma unroll
      for (int r = 0; r < 4; ++r) {
        size_t row = row0 + wm * 64 + i * 16 + quad * 4 + r;
        float pt = (float)pos[row];
        size_t rowoff = row * 2048 + col0;
#pragma unroll
        for (int j = 0; j < 2; ++j) {
          int f = g[j] * 16 + l16;   // f in [0,64)
          float ang = pt * __expf(-0.14391156831212787f * (float)f);
          float sn, cs;
          __sincosf(ang, &sn, &cs);
          cs *= mul; sn *= mul;
          float q0 = acc[i][j][r], q1 = acc[i][j + 2][r];
          C[rowoff + f]      = f2b(q0 * cs - q1 * sn);
          C[rowoff + f + 64] = f2b(q1 * cs + q0 * sn);
        }
      }
  } else {
#pragma unroll
    for (int i = 0; i < 4; ++i)
#pragma unroll
      for (int j = 0; j < 4; ++j) {
        size_t col = col0 + g[j] * 16 + l16;
        size_t rowb = row0 + wm * 64 + i * 16 + quad * 4;
        ushort4 ov;
        ov.x = f2b(acc[i][j][0]); ov.y = f2b(acc[i][j][1]);
        ov.z = f2b(acc[i][j][2]); ov.w = f2b(acc[i][j][3]);
        *(ushort4*)&Vt[col * 2048 + rowb] = ov;
      }
  }
}

// ---------------- flash attention: R5-verified (V LDS staging under K latency) ----------------
__global__ __launch_bounds__(256, 2) void k_attn(const ushort_t* __restrict__ Q,
                                                 const ushort_t* __restrict__ Kg,
                                                 const ushort_t* __restrict__ Vt,
                                                 ushort_t* __restrict__ O) {
  __shared__ uint32 smem[9216 + 256 + 8192];  // 69 KB: Qs 16K + Pbf 20K + Lred 1K + Vs 32K
  ushort_t* Qs  = (ushort_t*)smem;      // 64 x 128 bf16, swizzled: chunk c at c ^ (r&15)
  uint32*   Pbf = smem + 4096;          // 4 waves x 64 rows x 20 dwords (80 B stride)
  float*    Lred = (float*)(smem + 9216);  // [wave][qg][l16]
  ushort_t* Vs  = (ushort_t*)(smem + 9472); // 4 waves x 8KB V stage
  float*    Rbuf = (float*)smem;        // epilogue alias: [wave][16][132] = 8448 dw <= 9216

  const int tid = threadIdx.x;
  const int lane = tid & 63, wave = tid >> 6;
  const int quad = lane >> 4, l16 = lane & 15;
  const int bid = blockIdx.x;
  const int head = ((bid & 7) << 1) + ((bid >> 3) >> 5);
  const int qt = (bid >> 3) & 31;

#pragma unroll
  for (int j = 0; j < 4; ++j) {
    int s = tid + 256 * j;
    int r = s >> 4, p = s & 15;
    LDS_LOAD16(Q + (size_t)(qt * 64 + r) * 2048 + head * 128 + ((p ^ (r & 15)) * 8), &Qs[s * 8]);
  }
  __syncthreads();

  f32x4 zero = {0.f, 0.f, 0.f, 0.f};
  f32x4 oacc[4][8];
#pragma unroll
  for (int qg = 0; qg < 4; ++qg)
#pragma unroll
    for (int ns = 0; ns < 8; ++ns) oacc[qg][ns] = zero;
  float l_acc[4] = {0.f, 0.f, 0.f, 0.f};

  const ushort_t* Kbase = Kg + (size_t)head * 128;
  const ushort_t* Vbase = Vt + (size_t)head * 128 * 2048;
  uint32* pw = Pbf + wave * 1280;
  ushort_t* Vsw = Vs + wave * 4096;
  const ushort_t* Vst = Vbase + (size_t)(lane >> 2) * 2048 + ((lane & 3) ^ ((lane >> 3) & 3)) * 8;
  const int vsw = (quad ^ ((l16 >> 1) & 3)) * 8;  // read-side swizzled chunk offset

  for (int it = 0; it < 16; ++it) {
    const int kb = it * 128 + wave * 32;

#pragma unroll
    for (int l = 0; l < 8; ++l)
      LDS_LOAD16(Vst + (size_t)l * 16 * 2048 + kb, &Vsw[(l * 64 + lane) * 8]);

    short8 kf[2][4];
#pragma unroll
    for (int kg = 0; kg < 2; ++kg)
#pragma unroll
      for (int kk = 0; kk < 4; ++kk)
        kf[kg][kk] = *(const short8*)&Kbase[(size_t)(kb + kg * 16 + l16) * 2048 + kk * 32 + quad * 8];

#pragma unroll
    for (int qg = 0; qg < 4; ++qg) {
      short8 qa[4];
#pragma unroll
      for (int kk = 0; kk < 4; ++kk)
        qa[kk] = *(const short8*)&Qs[((qg * 16 + l16) * 16 + ((kk * 4 + quad) ^ l16)) * 8];
      f32x4 s0 = zero, s1 = zero;
#pragma unroll
      for (int kk = 0; kk < 4; ++kk) {
        s0 = __builtin_amdgcn_mfma_f32_16x16x32_bf16(kf[0][kk], qa[kk], s0, 0, 0, 0);
        s1 = __builtin_amdgcn_mfma_f32_16x16x32_bf16(kf[1][kk], qa[kk], s1, 0, 0, 0);
      }
      float p00 = __expf(s0[0]), p01 = __expf(s0[1]);
      float p02 = __expf(s0[2]), p03 = __expf(s0[3]);
      float p10 = __expf(s1[0]), p11 = __expf(s1[1]);
      float p12 = __expf(s1[2]), p13 = __expf(s1[3]);
      l_acc[qg] += ((p00 + p01) + (p02 + p03)) + ((p10 + p11) + (p12 + p13));
      u32x2 w0, w1;
      w0[0] = pk2(p00, p01); w0[1] = pk2(p02, p03);
      w1[0] = pk2(p10, p11); w1[1] = pk2(p12, p13);
      int off = (qg * 16 + l16) * 20 + quad * 2;
      *(u32x2*)&pw[off]     = w0;
      *(u32x2*)&pw[off + 8] = w1;
    }

    short8 pb[4];
#pragma unroll
    for (int qg = 0; qg < 4; ++qg)
      pb[qg] = *(const short8*)&pw[(qg * 16 + l16) * 20 + quad * 4];  // B-op: [n=qrow][k=key]

    asm volatile("s_waitcnt vmcnt(0)" ::: "memory");

#pragma unroll
    for (int ns = 0; ns < 8; ++ns) {
      const short8 vf = *(const short8*)&Vsw[(ns * 16 + l16) * 32 + vsw];
#pragma unroll
      for (int qg = 0; qg < 4; ++qg)
        oacc[qg][ns] = __builtin_amdgcn_mfma_f32_16x16x32_bf16(vf, pb[qg], oacc[qg][ns], 0, 0, 0);
    }

    asm volatile("s_waitcnt lgkmcnt(0)" ::: "memory");
  }

#pragma unroll
  for (int qg = 0; qg < 4; ++qg) {
    float l = l_acc[qg];
    l += __shfl_xor(l, 16, 64);
    l += __shfl_xor(l, 32, 64);
    l_acc[qg] = l;
  }
  if (quad == 0) {
#pragma unroll
    for (int qg = 0; qg < 4; ++qg) Lred[wave * 64 + qg * 16 + l16] = l_acc[qg];
  }

  const int tq = tid >> 4;
  const int td = (tid & 15) * 8;
  for (int qg = 0; qg < 4; ++qg) {
    __syncthreads();
#pragma unroll
    for (int ns = 0; ns < 8; ++ns)
      *(f32x4*)&Rbuf[(wave * 16 + l16) * 132 + ns * 16 + quad * 4] = oacc[qg][ns];
    __syncthreads();
    float lt = Lred[qg * 16 + tq] + Lred[64 + qg * 16 + tq] +
               Lred[128 + qg * 16 + tq] + Lred[192 + qg * 16 + tq];
    float inv = 1.0f / lt;
    f32x4 sA = zero, sB = zero;
#pragma unroll
    for (int w = 0; w < 4; ++w) {
      sA += *(const f32x4*)&Rbuf[(w * 16 + tq) * 132 + td];
      sB += *(const f32x4*)&Rbuf[(w * 16 + tq) * 132 + td + 4];
    }
    ushort4 o1, o2;
    o1.x = f2b(sA[0] * inv); o1.y = f2b(sA[1] * inv);
    o1.z = f2b(sA[2] * inv); o1.w = f2b(sA[3] * inv);
    o2.x = f2b(sB[0] * inv); o2.y = f2b(sB[1] * inv);
    o2.z = f2b(sB[2] * inv); o2.w = f2b(sB[3] * inv);
    size_t orow = (size_t)(qt * 64 + qg * 16 + tq) * 2048 + head * 128 + td;
    *(ushort4*)&O[orow] = o1;
    *(ushort4*)&O[orow + 4] = o2;
  }
}

// ---------------- Wo GEMM-BT, split-K=2: A via LDS rotation, B direct to regs ----------------
// grid (16,16,2): z selects K-half [z*1024, z*1024+1024). Partials to P[z*E + ...].
__global__ __launch_bounds__(256, 3) void k_gemm_wo_sk(const ushort_t* __restrict__ A,
                                                       const ushort_t* __restrict__ B,
                                                       float* __restrict__ P) {
  __shared__ ushort_t As[3][128 * 32];
  const int tid = threadIdx.x;
  const int lane = tid & 63, wave = tid >> 6;
  const int quad = lane >> 4, l16 = lane & 15;
  const int wm = wave >> 1, wn = wave & 1;
  const size_t row0 = (size_t)blockIdx.y * 128, col0 = (size_t)blockIdx.x * 128;
  const int k0 = blockIdx.z * 1024;
  float* Pz = P + (size_t)blockIdx.z * E;
  const ushort_t* Asrc = A + k0;

  const ushort_t* Bpt[4];
#pragma unroll
  for (int j = 0; j < 4; ++j)
    Bpt[j] = B + k0 + (size_t)(col0 + wn * 64 + j * 16 + l16) * 2048 + quad * 8;

  f32x4 zero = {0.f, 0.f, 0.f, 0.f};
  f32x4 acc[4][4];
#pragma unroll
  for (int i = 0; i < 4; ++i)
#pragma unroll
    for (int j = 0; j < 4; ++j) acc[i][j] = zero;

  short8 b0[4], b1[4];
  GPROLOGUE();

  for (int tt = 0; tt < 30; tt += 6) {
    GBODY(tt + 0, 0, 2, b0, b1, 1, 1, "vmcnt(6)");
    GBODY(tt + 1, 1, 0, b1, b0, 1, 1, "vmcnt(6)");
    GBODY(tt + 2, 2, 1, b0, b1, 1, 1, "vmcnt(6)");
    GBODY(tt + 3, 0, 2, b1, b0, 1, 1, "vmcnt(6)");
    GBODY(tt + 4, 1, 0, b0, b1, 1, 1, "vmcnt(6)");
    GBODY(tt + 5, 2, 1, b1, b0, 1, 1, "vmcnt(6)");
  }
  GBODY(30, 0, 0, b0, b1, 0, 1, "vmcnt(4)");   // loads B(31); retires A(31)
  GFRAGS(As[1], b1);                           // body 31

#pragma unroll
  for (int i = 0; i < 4; ++i)
#pragma unroll
    for (int j = 0; j < 4; ++j)
#pragma unroll
      for (int r = 0; r < 4; ++r) {
        size_t row = row0 + wm * 64 + i * 16 + quad * 4 + r;
        size_t col = col0 + wn * 64 + j * 16 + l16;
        Pz[row * 2048 + col] = acc[i][j][r];
      }
}

// ---------------- split-K reduce: out = P0 + P1 (fp32) ----------------
__global__ __launch_bounds__(256) void k_red(const float* __restrict__ P, float* __restrict__ out) {
  size_t i = ((size_t)blockIdx.x * 256 + threadIdx.x) * 4;
  f32x4 a = *(const f32x4*)(P + i);
  f32x4 b = *(const f32x4*)(P + E + i);
  *(f32x4*)(out + i) = a + b;
}

extern "C" void kernel_launch(void* const* d_in, const int* in_sizes, int n_in,
                              void* d_out, int out_size, void* d_ws, size_t ws_size,
                              hipStream_t stream) {
  const float* X  = (const float*)d_in[0];
  const float* wq = (const float*)d_in[1];
  const float* wk = (const float*)d_in[2];
  const float* wv = (const float*)d_in[3];
  const float* wo = (const float*)d_in[4];
  const int*  pos = (const int*)d_in[5];
  float* out = (float*)d_out;

  if (ws_size < 9 * E * sizeof(ushort_t)) return;  // need 72 MB scratch

  ushort_t* Xb  = (ushort_t*)d_ws;
  ushort_t* Wqb = Xb + E;
  ushort_t* Wkb = Xb + 2 * E;
  ushort_t* Wvb = Xb + 3 * E;
  ushort_t* Wob = Xb + 4 * E;
  ushort_t* Qm  = Xb + 5 * E;
  ushort_t* Km  = Xb + 6 * E;
  ushort_t* Vtm = Xb + 7 * E;
  ushort_t* Om  = Xb + 8 * E;
  // After k_attn, Xb..Wvb (4E ushorts = 32 MB) are dead: reuse as 2x fp32 partial planes.
  float* Pf = (float*)Xb;   // P0 = [0,E) floats, P1 = [E,2E) floats

  dim3 b256(256);
  k_cvt5<<<dim3(4096, 5), b256, 0, stream>>>(X, wq, wk, wv, wo, Xb);
  k_gemm_qkv<<<dim3(16, 16, 3), b256, 0, stream>>>(Xb, Wqb, Wkb, Wvb, Qm, Km, Vtm, pos);
  k_attn<<<512, b256, 0, stream>>>(Qm, Km, Vtm, Om);
  k_gemm_wo_sk<<<dim3(16, 16, 2), b256, 0, stream>>>(Om, Wob, Pf);
  k_red<<<4096, b256, 0, stream>>>(Pf, out);
}

// Round 7
// 294.823 us; speedup vs baseline: 1.0889x; 1.0889x over previous
//
#include <hip/hip_runtime.h>

typedef unsigned short ushort_t;
typedef unsigned int uint32;
typedef __attribute__((ext_vector_type(8))) short short8;
typedef __attribute__((ext_vector_type(4))) float f32x4;
typedef __attribute__((ext_vector_type(2))) uint32 u32x2;

#define LDS_LOAD16(gptr, lptr)                                                             \
  __builtin_amdgcn_global_load_lds((const __attribute__((address_space(1))) uint32*)(gptr),\
                                   (__attribute__((address_space(3))) uint32*)(lptr),      \
                                   16, 0, 0)

__device__ __forceinline__ ushort_t f2b(float f) {
  uint32 u = __builtin_bit_cast(uint32, f);
  u += 0x7fffu + ((u >> 16) & 1u);   // RNE
  return (ushort_t)(u >> 16);
}
__device__ __forceinline__ uint32 pk2(float a, float b) {
  return (uint32)f2b(a) | ((uint32)f2b(b) << 16);
}

constexpr size_t E = (size_t)2048 * 2048;

// ---------------- fused fp32 -> bf16 convert (all 5 tensors) ----------------
__global__ __launch_bounds__(256) void k_cvt5(const float* __restrict__ a0, const float* __restrict__ a1,
                                              const float* __restrict__ a2, const float* __restrict__ a3,
                                              const float* __restrict__ a4, ushort_t* __restrict__ out) {
  const float* srcs[5] = {a0, a1, a2, a3, a4};
  const float* s = srcs[blockIdx.y];
  size_t i = ((size_t)blockIdx.x * 256 + threadIdx.x) * 4;
  float4 v = *(const float4*)(s + i);
  ushort4 o;
  o.x = f2b(v.x); o.y = f2b(v.y); o.z = f2b(v.z); o.w = f2b(v.w);
  *(ushort4*)(out + (size_t)blockIdx.y * E + i) = o;
}

// ===================== 3-buffer BK=32 rotating GEMM pipeline (R5-verified, 70us) =====================
// R6 post-mortem: B direct-to-reg regressed (FETCH 45->67MB, 1-body prefetch distance) —
// LDS staging of B does dedup+coalescing, not just bandwidth. Keep BOTH operands staged.
#define SWZ3(r) (((r) >> 1) & 3)

#define STG32(srcA, srcB, dA, dB, ktile)                                        \
  do {                                                                          \
    const int koff_ = (ktile) * 32;                                             \
    _Pragma("unroll") for (int j2_ = 0; j2_ < 2; ++j2_) {                       \
      int c_ = tid + 256 * j2_;                                                 \
      int r_ = c_ >> 2, p_ = c_ & 3;                                            \
      int sc_ = (p_ ^ SWZ3(r_)) * 8;                                            \
      LDS_LOAD16((srcA) + (row0 + r_) * 2048 + koff_ + sc_, &(dA)[c_ * 8]);     \
      LDS_LOAD16((srcB) + (col0 + r_) * 2048 + koff_ + sc_, &(dB)[c_ * 8]);     \
    }                                                                           \
  } while (0)

// ---------------- fused QKV GEMM-BT, fused RoPE epilogue ----------------
__global__ __launch_bounds__(256, 3) void k_gemm_qkv(const ushort_t* __restrict__ A,
                                                     const ushort_t* __restrict__ B0,
                                                     const ushort_t* __restrict__ B1,
                                                     const ushort_t* __restrict__ B2,
                                                     ushort_t* __restrict__ Qm,
                                                     ushort_t* __restrict__ Km,
                                                     ushort_t* __restrict__ Vt,
                                                     const int* __restrict__ pos) {
  __shared__ ushort_t As[3][128 * 32];
  __shared__ ushort_t Bs[3][128 * 32];
  const int tid = threadIdx.x;
  const int lane = tid & 63, wave = tid >> 6;
  const int quad = lane >> 4, l16 = lane & 15;
  const int wm = wave >> 1, wn = wave & 1;
  const int z = blockIdx.z;
  const ushort_t* Bp = (z == 0) ? B0 : (z == 1) ? B1 : B2;
  const size_t row0 = (size_t)blockIdx.y * 128, col0 = (size_t)blockIdx.x * 128;

  int g[4];
#pragma unroll
  for (int j = 0; j < 4; ++j) g[j] = (j & 1) + ((j >> 1) << 2) + wn * 2;  // {0,1,4,5}/{2,3,6,7}

  f32x4 zero = {0.f, 0.f, 0.f, 0.f};
  f32x4 acc[4][4];
#pragma unroll
  for (int i = 0; i < 4; ++i)
#pragma unroll
    for (int j = 0; j < 4; ++j) acc[i][j] = zero;

#define QKV_FRAGS(CUR)                                                          \
    short8 a_[4], b_[4];                                                        \
    _Pragma("unroll") for (int i_ = 0; i_ < 4; ++i_) {                          \
      int ra_ = wm * 64 + i_ * 16 + l16;                                        \
      a_[i_] = *(const short8*)&As[CUR][(ra_ * 4 + (quad ^ SWZ3(ra_))) * 8];    \
    }                                                                           \
    _Pragma("unroll") for (int j_ = 0; j_ < 4; ++j_) {                          \
      int rb_ = g[j_] * 16 + l16;                                               \
      b_[j_] = *(const short8*)&Bs[CUR][(rb_ * 4 + (quad ^ SWZ3(rb_))) * 8];    \
    }                                                                           \
    _Pragma("unroll") for (int i_ = 0; i_ < 4; ++i_)                            \
      _Pragma("unroll") for (int j_ = 0; j_ < 4; ++j_)                          \
        acc[i_][j_] = __builtin_amdgcn_mfma_f32_16x16x32_bf16(a_[i_], b_[j_], acc[i_][j_], 0, 0, 0);

#define QKV_BODY(T, CUR, STG, SEN, VM)                                          \
  do {                                                                          \
    if (SEN) STG32(A, Bp, As[STG], Bs[STG], (T) + 2);                           \
    QKV_FRAGS(CUR)                                                              \
    asm volatile("s_waitcnt " VM ::: "memory");                                 \
    __builtin_amdgcn_s_barrier();                                               \
  } while (0)

  STG32(A, Bp, As[0], Bs[0], 0);
  STG32(A, Bp, As[1], Bs[1], 1);
  asm volatile("s_waitcnt vmcnt(4)" ::: "memory");
  __builtin_amdgcn_s_barrier();

  for (int tt = 0; tt < 60; tt += 3) {
    QKV_BODY(tt + 0, 0, 2, 1, "vmcnt(4)");
    QKV_BODY(tt + 1, 1, 0, 1, "vmcnt(4)");
    QKV_BODY(tt + 2, 2, 1, 1, "vmcnt(4)");
  }
  QKV_BODY(60, 0, 2, 1, "vmcnt(4)");
  QKV_BODY(61, 1, 0, 1, "vmcnt(4)");   // stages tile 63 into buf 0
  QKV_BODY(62, 2, 1, 0, "vmcnt(0)");   // no stage left; retire tile 63
  { QKV_FRAGS(0) }                     // t=63, no wait/barrier needed

  if (z < 2) {
    ushort_t* C = z ? Km : Qm;
    const float mul = z ? 1.0f : 0.08838834764831845f;  // fold 1/sqrt(128) into Q
#pragma unroll
    for (int i = 0; i < 4; ++i)
#pragma unroll
      for (int r = 0; r < 4; ++r) {
        size_t row = row0 + wm * 64 + i * 16 + quad * 4 + r;
        float pt = (float)pos[row];
        size_t rowoff = row * 2048 + col0;
#pragma unroll
        for (int j = 0; j < 2; ++j) {
          int f = g[j] * 16 + l16;   // f in [0,64)
          float ang = pt * __expf(-0.14391156831212787f * (float)f);
          float sn, cs;
          __sincosf(ang, &sn, &cs);
          cs *= mul; sn *= mul;
          float q0 = acc[i][j][r], q1 = acc[i][j + 2][r];
          C[rowoff + f]      = f2b(q0 * cs - q1 * sn);
          C[rowoff + f + 64] = f2b(q1 * cs + q0 * sn);
        }
      }
  } else {
#pragma unroll
    for (int i = 0; i < 4; ++i)
#pragma unroll
      for (int j = 0; j < 4; ++j) {
        size_t col = col0 + g[j] * 16 + l16;
        size_t rowb = row0 + wm * 64 + i * 16 + quad * 4;
        ushort4 ov;
        ov.x = f2b(acc[i][j][0]); ov.y = f2b(acc[i][j][1]);
        ov.z = f2b(acc[i][j][2]); ov.w = f2b(acc[i][j][3]);
        *(ushort4*)&Vt[col * 2048 + rowb] = ov;
      }
  }
}

// ---------------- flash attention: 32 q-rows/block + V LDS staging + K register dbuf ----------------
// Grid 1024 = 16 heads x 64 q-tiles, XCD-clustered (2 heads/XCD -> K+V 2MB, L2-fit).
// R3's verified 32-row geometry at __launch_bounds__(256,2) (R3 failed only from occupancy-4
// spill): acc 64 + K-dbuf 64 + working ~80 fits 256 unified regs, no spill, 2 blocks/CU.
// Per iter: issue V stage (R5-verified swizzle), issue NEXT iter's K to shadow regs (full
// iteration of distance), QK from current K regs, softmax, vmcnt(8) (V landed, K-next still
// in flight), PV from LDS, lgkmcnt(0) WAR fence. Last iter drains vmcnt(0).
__global__ __launch_bounds__(256, 2) void k_attn(const ushort_t* __restrict__ Q,
                                                 const ushort_t* __restrict__ Kg,
                                                 const ushort_t* __restrict__ Vt,
                                                 ushort_t* __restrict__ O) {
  __shared__ uint32 smem[8576 + 8192];  // 67KB: Qs 8K + Pbf 10K (+Rbuf alias 33K) + Lred .5K + Vs 32K
  ushort_t* Qs  = (ushort_t*)smem;      // 32 x 128 bf16, swizzled: chunk c at c ^ (r&15)
  uint32*   Pbf = smem + 2048;          // 4 waves x 32 rows x 20 dwords (80 B stride)
  float*    Lred = (float*)(smem + 8448);   // [wave][qg][l16] (128 dw)
  ushort_t* Vs  = (ushort_t*)(smem + 8576); // 4 waves x 8KB V stage
  float*    Rbuf = (float*)smem;        // epilogue alias: [wave][16][132] = 8448 dw

  const int tid = threadIdx.x;
  const int lane = tid & 63, wave = tid >> 6;
  const int quad = lane >> 4, l16 = lane & 15;
  const int bid = blockIdx.x;
  const int tb = bid >> 3;
  const int head = ((bid & 7) << 1) + (tb >> 6);
  const int qt = tb & 63;

#pragma unroll
  for (int j = 0; j < 2; ++j) {
    int s = tid + 256 * j;
    int r = s >> 4, p = s & 15;
    LDS_LOAD16(Q + (size_t)(qt * 32 + r) * 2048 + head * 128 + ((p ^ (r & 15)) * 8), &Qs[s * 8]);
  }
  __syncthreads();

  f32x4 zero = {0.f, 0.f, 0.f, 0.f};
  f32x4 oacc[2][8];
#pragma unroll
  for (int qg = 0; qg < 2; ++qg)
#pragma unroll
    for (int ns = 0; ns < 8; ++ns) oacc[qg][ns] = zero;
  float l_acc[2] = {0.f, 0.f};

  const ushort_t* Kbase = Kg + (size_t)head * 128;
  const ushort_t* Vbase = Vt + (size_t)head * 128 * 2048;
  uint32* pw = Pbf + wave * 640;
  ushort_t* Vsw = Vs + wave * 4096;
  // V stage addressing (R5-verified): linear LDS dest, pre-swizzled global source
  const ushort_t* Vst = Vbase + (size_t)(lane >> 2) * 2048 + ((lane & 3) ^ ((lane >> 3) & 3)) * 8;
  const int vsw = (quad ^ ((l16 >> 1) & 3)) * 8;  // read-side swizzled chunk offset

#define KLOAD(DST, KB)                                                           \
  _Pragma("unroll") for (int kg_ = 0; kg_ < 2; ++kg_)                            \
    _Pragma("unroll") for (int kk_ = 0; kk_ < 4; ++kk_)                          \
      (DST)[kg_][kk_] = *(const short8*)&Kbase[(size_t)((KB) + kg_ * 16 + l16) * 2048 + kk_ * 32 + quad * 8];

#define ATTN_IT(KC, KN, T, LOADN, VMW)                                           \
  do {                                                                           \
    const int kb_ = (T) * 128 + wave * 32;                                       \
    _Pragma("unroll") for (int l_ = 0; l_ < 8; ++l_)                             \
      LDS_LOAD16(Vst + (size_t)l_ * 16 * 2048 + kb_, &Vsw[(l_ * 64 + lane) * 8]);\
    if (LOADN) { KLOAD(KN, kb_ + 128); }                                         \
    _Pragma("unroll") for (int kg = 0; kg < 2; ++kg) {                           \
      _Pragma("unroll") for (int qg = 0; qg < 2; ++qg) {                         \
        f32x4 s = zero;                                                          \
        _Pragma("unroll") for (int kk = 0; kk < 4; ++kk) {                       \
          short8 qa = *(const short8*)&Qs[((qg * 16 + l16) * 16 + ((kk * 4 + quad) ^ l16)) * 8]; \
          s = __builtin_amdgcn_mfma_f32_16x16x32_bf16((KC)[kg][kk], qa, s, 0, 0, 0); \
        }                                                                        \
        float p0 = __expf(s[0]), p1 = __expf(s[1]);                              \
        float p2 = __expf(s[2]), p3 = __expf(s[3]);                              \
        l_acc[qg] += (p0 + p1) + (p2 + p3);                                      \
        u32x2 w; w[0] = pk2(p0, p1); w[1] = pk2(p2, p3);                         \
        *(u32x2*)&pw[(qg * 16 + l16) * 20 + kg * 8 + quad * 2] = w;              \
      }                                                                          \
    }                                                                            \
    short8 pb[2];                                                                \
    _Pragma("unroll") for (int qg = 0; qg < 2; ++qg)                             \
      pb[qg] = *(const short8*)&pw[(qg * 16 + l16) * 20 + quad * 4];             \
    asm volatile("s_waitcnt " VMW ::: "memory");                                 \
    _Pragma("unroll") for (int ns = 0; ns < 8; ++ns) {                           \
      const short8 vf = *(const short8*)&Vsw[(ns * 16 + l16) * 32 + vsw];        \
      _Pragma("unroll") for (int qg = 0; qg < 2; ++qg)                           \
        oacc[qg][ns] = __builtin_amdgcn_mfma_f32_16x16x32_bf16(vf, pb[qg], oacc[qg][ns], 0, 0, 0); \
    }                                                                            \
    asm volatile("s_waitcnt lgkmcnt(0)" ::: "memory");                           \
  } while (0)

  short8 kfA[2][4], kfB[2][4];
  KLOAD(kfA, wave * 32);   // iter 0's K

  for (int it2 = 0; it2 < 14; it2 += 2) {
    ATTN_IT(kfA, kfB, it2 + 0, 1, "vmcnt(8)");
    ATTN_IT(kfB, kfA, it2 + 1, 1, "vmcnt(8)");
  }
  ATTN_IT(kfA, kfB, 14, 1, "vmcnt(8)");
  ATTN_IT(kfB, kfA, 15, 0, "vmcnt(0)");

#pragma unroll
  for (int qg = 0; qg < 2; ++qg) {
    float l = l_acc[qg];
    l += __shfl_xor(l, 16, 64);
    l += __shfl_xor(l, 32, 64);
    l_acc[qg] = l;
  }
  if (quad == 0) {
#pragma unroll
    for (int qg = 0; qg < 2; ++qg) Lred[wave * 32 + qg * 16 + l16] = l_acc[qg];
  }

  const int tq = tid >> 4;
  const int td = (tid & 15) * 8;
  for (int qg = 0; qg < 2; ++qg) {
    __syncthreads();   // pass 0: Qs/Pbf dead, Lred visible; later: Rbuf free
#pragma unroll
    for (int ns = 0; ns < 8; ++ns)
      *(f32x4*)&Rbuf[(wave * 16 + l16) * 132 + ns * 16 + quad * 4] = oacc[qg][ns];
    __syncthreads();
    float lt = Lred[qg * 16 + tq] + Lred[32 + qg * 16 + tq] +
               Lred[64 + qg * 16 + tq] + Lred[96 + qg * 16 + tq];
    float inv = 1.0f / lt;
    f32x4 sA = zero, sB = zero;
#pragma unroll
    for (int w = 0; w < 4; ++w) {
      sA += *(const f32x4*)&Rbuf[(w * 16 + tq) * 132 + td];
      sB += *(const f32x4*)&Rbuf[(w * 16 + tq) * 132 + td + 4];
    }
    ushort4 o1, o2;
    o1.x = f2b(sA[0] * inv); o1.y = f2b(sA[1] * inv);
    o1.z = f2b(sA[2] * inv); o1.w = f2b(sA[3] * inv);
    o2.x = f2b(sB[0] * inv); o2.y = f2b(sB[1] * inv);
    o2.z = f2b(sB[2] * inv); o2.w = f2b(sB[3] * inv);
    size_t orow = (size_t)(qt * 32 + qg * 16 + tq) * 2048 + head * 128 + td;
    *(ushort4*)&O[orow] = o1;
    *(ushort4*)&O[orow + 4] = o2;
  }
}

// ---------------- Wo GEMM-BT, split-K=2: 128x128 tile, 3-buffer BK=32 pipeline (R5) ----------------
__global__ __launch_bounds__(256, 3) void k_gemm_wo_sk(const ushort_t* __restrict__ A,
                                                       const ushort_t* __restrict__ B,
                                                       float* __restrict__ P) {
  __shared__ ushort_t As[3][128 * 32];
  __shared__ ushort_t Bs[3][128 * 32];
  const int tid = threadIdx.x;
  const int lane = tid & 63, wave = tid >> 6;
  const int quad = lane >> 4, l16 = lane & 15;
  const int wm = wave >> 1, wn = wave & 1;
  const size_t row0 = (size_t)blockIdx.y * 128, col0 = (size_t)blockIdx.x * 128;
  const int k0 = blockIdx.z * 1024;
  float* Pz = P + (size_t)blockIdx.z * E;
  const ushort_t* Ak = A + k0;
  const ushort_t* Bk = B + k0;

  f32x4 zero = {0.f, 0.f, 0.f, 0.f};
  f32x4 acc[4][4];
#pragma unroll
  for (int i = 0; i < 4; ++i)
#pragma unroll
    for (int j = 0; j < 4; ++j) acc[i][j] = zero;

#define WO_FRAGS(CUR)                                                           \
    short8 a_[4], b_[4];                                                        \
    _Pragma("unroll") for (int i_ = 0; i_ < 4; ++i_) {                          \
      int ra_ = wm * 64 + i_ * 16 + l16;                                        \
      a_[i_] = *(const short8*)&As[CUR][(ra_ * 4 + (quad ^ SWZ3(ra_))) * 8];    \
    }                                                                           \
    _Pragma("unroll") for (int j_ = 0; j_ < 4; ++j_) {                          \
      int rb_ = wn * 64 + j_ * 16 + l16;                                        \
      b_[j_] = *(const short8*)&Bs[CUR][(rb_ * 4 + (quad ^ SWZ3(rb_))) * 8];    \
    }                                                                           \
    _Pragma("unroll") for (int i_ = 0; i_ < 4; ++i_)                            \
      _Pragma("unroll") for (int j_ = 0; j_ < 4; ++j_)                          \
        acc[i_][j_] = __builtin_amdgcn_mfma_f32_16x16x32_bf16(a_[i_], b_[j_], acc[i_][j_], 0, 0, 0);

#define WO_BODY(T, CUR, STG, SEN, VM)                                           \
  do {                                                                          \
    if (SEN) STG32(Ak, Bk, As[STG], Bs[STG], (T) + 2);                          \
    WO_FRAGS(CUR)                                                               \
    asm volatile("s_waitcnt " VM ::: "memory");                                 \
    __builtin_amdgcn_s_barrier();                                               \
  } while (0)

  STG32(Ak, Bk, As[0], Bs[0], 0);
  STG32(Ak, Bk, As[1], Bs[1], 1);
  asm volatile("s_waitcnt vmcnt(4)" ::: "memory");
  __builtin_amdgcn_s_barrier();

  for (int tt = 0; tt < 27; tt += 3) {
    WO_BODY(tt + 0, 0, 2, 1, "vmcnt(4)");
    WO_BODY(tt + 1, 1, 0, 1, "vmcnt(4)");
    WO_BODY(tt + 2, 2, 1, 1, "vmcnt(4)");
  }
  WO_BODY(27, 0, 2, 1, "vmcnt(4)");
  WO_BODY(28, 1, 0, 1, "vmcnt(4)");
  WO_BODY(29, 2, 1, 1, "vmcnt(4)");    // stages tile 31 into buf 1
  WO_BODY(30, 0, 2, 0, "vmcnt(0)");    // no stage left; retire tile 31
  { WO_FRAGS(1) }                      // t=31, no wait/barrier needed

#pragma unroll
  for (int i = 0; i < 4; ++i)
#pragma unroll
    for (int j = 0; j < 4; ++j)
#pragma unroll
      for (int r = 0; r < 4; ++r) {
        size_t row = row0 + wm * 64 + i * 16 + quad * 4 + r;
        size_t col = col0 + wn * 64 + j * 16 + l16;
        Pz[row * 2048 + col] = acc[i][j][r];
      }
}

// ---------------- split-K reduce: out = P0 + P1 (fp32) ----------------
__global__ __launch_bounds__(256) void k_red(const float* __restrict__ P, float* __restrict__ out) {
  size_t i = ((size_t)blockIdx.x * 256 + threadIdx.x) * 4;
  f32x4 a = *(const f32x4*)(P + i);
  f32x4 b = *(const f32x4*)(P + E + i);
  *(f32x4*)(out + i) = a + b;
}

extern "C" void kernel_launch(void* const* d_in, const int* in_sizes, int n_in,
                              void* d_out, int out_size, void* d_ws, size_t ws_size,
                              hipStream_t stream) {
  const float* X  = (const float*)d_in[0];
  const float* wq = (const float*)d_in[1];
  const float* wk = (const float*)d_in[2];
  const float* wv = (const float*)d_in[3];
  const float* wo = (const float*)d_in[4];
  const int*  pos = (const int*)d_in[5];
  float* out = (float*)d_out;

  if (ws_size < 9 * E * sizeof(ushort_t)) return;  // need 72 MB scratch

  ushort_t* Xb  = (ushort_t*)d_ws;
  ushort_t* Wqb = Xb + E;
  ushort_t* Wkb = Xb + 2 * E;
  ushort_t* Wvb = Xb + 3 * E;
  ushort_t* Wob = Xb + 4 * E;
  ushort_t* Qm  = Xb + 5 * E;
  ushort_t* Km  = Xb + 6 * E;
  ushort_t* Vtm = Xb + 7 * E;
  ushort_t* Om  = Xb + 8 * E;
  // After k_attn, Xb..Wvb (4E ushorts = 32 MB) are dead: reuse as 2x fp32 partial planes.
  float* Pf = (float*)Xb;   // P0 = [0,E) floats, P1 = [E,2E) floats

  dim3 b256(256);
  k_cvt5<<<dim3(4096, 5), b256, 0, stream>>>(X, wq, wk, wv, wo, Xb);
  k_gemm_qkv<<<dim3(16, 16, 3), b256, 0, stream>>>(Xb, Wqb, Wkb, Wvb, Qm, Km, Vtm, pos);
  k_attn<<<1024, b256, 0, stream>>>(Qm, Km, Vtm, Om);
  k_gemm_wo_sk<<<dim3(16, 16, 2), b256, 0, stream>>>(Om, Wob, Pf);
  k_red<<<4096, b256, 0, stream>>>(Pf, out);
}

// Round 8
// 266.659 us; speedup vs baseline: 1.2039x; 1.1056x over previous
//
#include <hip/hip_runtime.h>

typedef unsigned short ushort_t;
typedef unsigned int uint32;
typedef __attribute__((ext_vector_type(8))) short short8;
typedef __attribute__((ext_vector_type(4))) float f32x4;
typedef __attribute__((ext_vector_type(2))) uint32 u32x2;

#define LDS_LOAD16(gptr, lptr)                                                             \
  __builtin_amdgcn_global_load_lds((const __attribute__((address_space(1))) uint32*)(gptr),\
                                   (__attribute__((address_space(3))) uint32*)(lptr),      \
                                   16, 0, 0)

__device__ __forceinline__ ushort_t f2b(float f) {
  uint32 u = __builtin_bit_cast(uint32, f);
  u += 0x7fffu + ((u >> 16) & 1u);   // RNE
  return (ushort_t)(u >> 16);
}
__device__ __forceinline__ uint32 pk2(float a, float b) {
  return (uint32)f2b(a) | ((uint32)f2b(b) << 16);
}

constexpr size_t E = (size_t)2048 * 2048;

// ---------------- fused fp32 -> bf16 convert (all 5 tensors) ----------------
__global__ __launch_bounds__(256) void k_cvt5(const float* __restrict__ a0, const float* __restrict__ a1,
                                              const float* __restrict__ a2, const float* __restrict__ a3,
                                              const float* __restrict__ a4, ushort_t* __restrict__ out) {
  const float* srcs[5] = {a0, a1, a2, a3, a4};
  const float* s = srcs[blockIdx.y];
  size_t i = ((size_t)blockIdx.x * 256 + threadIdx.x) * 4;
  float4 v = *(const float4*)(s + i);
  ushort4 o;
  o.x = f2b(v.x); o.y = f2b(v.y); o.z = f2b(v.z); o.w = f2b(v.w);
  *(ushort4*)(out + (size_t)blockIdx.y * E + i) = o;
}

// ===================== 3-buffer BK=32 rotating GEMM pipeline (R5-verified, 70us) =====================
#define SWZ3(r) (((r) >> 1) & 3)

#define STG32(srcA, srcB, dA, dB, ktile)                                        \
  do {                                                                          \
    const int koff_ = (ktile) * 32;                                             \
    _Pragma("unroll") for (int j2_ = 0; j2_ < 2; ++j2_) {                       \
      int c_ = tid + 256 * j2_;                                                 \
      int r_ = c_ >> 2, p_ = c_ & 3;                                            \
      int sc_ = (p_ ^ SWZ3(r_)) * 8;                                            \
      LDS_LOAD16((srcA) + (row0 + r_) * 2048 + koff_ + sc_, &(dA)[c_ * 8]);     \
      LDS_LOAD16((srcB) + (col0 + r_) * 2048 + koff_ + sc_, &(dB)[c_ * 8]);     \
    }                                                                           \
  } while (0)

// ---------------- fused QKV GEMM-BT, fused RoPE epilogue ----------------
__global__ __launch_bounds__(256, 3) void k_gemm_qkv(const ushort_t* __restrict__ A,
                                                     const ushort_t* __restrict__ B0,
                                                     const ushort_t* __restrict__ B1,
                                                     const ushort_t* __restrict__ B2,
                                                     ushort_t* __restrict__ Qm,
                                                     ushort_t* __restrict__ Km,
                                                     ushort_t* __restrict__ Vt,
                                                     const int* __restrict__ pos) {
  __shared__ ushort_t As[3][128 * 32];
  __shared__ ushort_t Bs[3][128 * 32];
  const int tid = threadIdx.x;
  const int lane = tid & 63, wave = tid >> 6;
  const int quad = lane >> 4, l16 = lane & 15;
  const int wm = wave >> 1, wn = wave & 1;
  const int z = blockIdx.z;
  const ushort_t* Bp = (z == 0) ? B0 : (z == 1) ? B1 : B2;
  const size_t row0 = (size_t)blockIdx.y * 128, col0 = (size_t)blockIdx.x * 128;

  int g[4];
#pragma unroll
  for (int j = 0; j < 4; ++j) g[j] = (j & 1) + ((j >> 1) << 2) + wn * 2;  // {0,1,4,5}/{2,3,6,7}

  f32x4 zero = {0.f, 0.f, 0.f, 0.f};
  f32x4 acc[4][4];
#pragma unroll
  for (int i = 0; i < 4; ++i)
#pragma unroll
    for (int j = 0; j < 4; ++j) acc[i][j] = zero;

#define QKV_FRAGS(CUR)                                                          \
    short8 a_[4], b_[4];                                                        \
    _Pragma("unroll") for (int i_ = 0; i_ < 4; ++i_) {                          \
      int ra_ = wm * 64 + i_ * 16 + l16;                                        \
      a_[i_] = *(const short8*)&As[CUR][(ra_ * 4 + (quad ^ SWZ3(ra_))) * 8];    \
    }                                                                           \
    _Pragma("unroll") for (int j_ = 0; j_ < 4; ++j_) {                          \
      int rb_ = g[j_] * 16 + l16;                                               \
      b_[j_] = *(const short8*)&Bs[CUR][(rb_ * 4 + (quad ^ SWZ3(rb_))) * 8];    \
    }                                                                           \
    _Pragma("unroll") for (int i_ = 0; i_ < 4; ++i_)                            \
      _Pragma("unroll") for (int j_ = 0; j_ < 4; ++j_)                          \
        acc[i_][j_] = __builtin_amdgcn_mfma_f32_16x16x32_bf16(a_[i_], b_[j_], acc[i_][j_], 0, 0, 0);

#define QKV_BODY(T, CUR, STG, SEN, VM)                                          \
  do {                                                                          \
    if (SEN) STG32(A, Bp, As[STG], Bs[STG], (T) + 2);                           \
    QKV_FRAGS(CUR)                                                              \
    asm volatile("s_waitcnt " VM ::: "memory");                                 \
    __builtin_amdgcn_s_barrier();                                               \
  } while (0)

  STG32(A, Bp, As[0], Bs[0], 0);
  STG32(A, Bp, As[1], Bs[1], 1);
  asm volatile("s_waitcnt vmcnt(4)" ::: "memory");
  __builtin_amdgcn_s_barrier();

  for (int tt = 0; tt < 60; tt += 3) {
    QKV_BODY(tt + 0, 0, 2, 1, "vmcnt(4)");
    QKV_BODY(tt + 1, 1, 0, 1, "vmcnt(4)");
    QKV_BODY(tt + 2, 2, 1, 1, "vmcnt(4)");
  }
  QKV_BODY(60, 0, 2, 1, "vmcnt(4)");
  QKV_BODY(61, 1, 0, 1, "vmcnt(4)");   // stages tile 63 into buf 0
  QKV_BODY(62, 2, 1, 0, "vmcnt(0)");   // no stage left; retire tile 63
  { QKV_FRAGS(0) }                     // t=63, no wait/barrier needed

  if (z < 2) {
    ushort_t* C = z ? Km : Qm;
    const float mul = z ? 1.0f : 0.08838834764831845f;  // fold 1/sqrt(128) into Q
#pragma unroll
    for (int i = 0; i < 4; ++i)
#pragma unroll
      for (int r = 0; r < 4; ++r) {
        size_t row = row0 + wm * 64 + i * 16 + quad * 4 + r;
        float pt = (float)pos[row];
        size_t rowoff = row * 2048 + col0;
#pragma unroll
        for (int j = 0; j < 2; ++j) {
          int f = g[j] * 16 + l16;   // f in [0,64)
          float ang = pt * __expf(-0.14391156831212787f * (float)f);
          float sn, cs;
          __sincosf(ang, &sn, &cs);
          cs *= mul; sn *= mul;
          float q0 = acc[i][j][r], q1 = acc[i][j + 2][r];
          C[rowoff + f]      = f2b(q0 * cs - q1 * sn);
          C[rowoff + f + 64] = f2b(q1 * cs + q0 * sn);
        }
      }
  } else {
#pragma unroll
    for (int i = 0; i < 4; ++i)
#pragma unroll
      for (int j = 0; j < 4; ++j) {
        size_t col = col0 + g[j] * 16 + l16;
        size_t rowb = row0 + wm * 64 + i * 16 + quad * 4;
        ushort4 ov;
        ov.x = f2b(acc[i][j][0]); ov.y = f2b(acc[i][j][1]);
        ov.z = f2b(acc[i][j][2]); ov.w = f2b(acc[i][j][3]);
        *(ushort4*)&Vt[col * 2048 + rowb] = ov;
      }
  }
}

// ---------------- flash attention v8: 512 threads, 1 block/CU, Q-in-regs, K/V LDS-staged ----------------
// Grid 256 = exactly 1 block/CU (16 heads x 16 q-tiles of 128 rows), XCD-clustered.
// Wave w: qh=w>>1 (32 q-rows), kh=w&1 (64 keys of the 128-key iter tile).
// Q in registers (qr[2][4], loaded once) — kills the 16KB/iter/wave LDS re-read.
// K staged coalesced via gl_lds with Q-style swizzle (slot c holds global chunk c^(r&15)),
// double-buffered: K(t+1) prefetched during body t, retired by vmcnt(0) at body end.
// V staged same-iter (single buffer): issued first, vmcnt(4) before mid-body barrier.
// P via 8KB XOR-grouped LDS: row stride 32 dw, dw-group g stored at g^(r&7).
// LDS = Ks 2x32K + Vs 32K + P 32K = 128 KB (m201-proven size).
__global__ __launch_bounds__(512, 2) void k_attn(const ushort_t* __restrict__ Q,
                                                 const ushort_t* __restrict__ Kg,
                                                 const ushort_t* __restrict__ Vt,
                                                 ushort_t* __restrict__ O) {
  __shared__ uint32 smem[32768];            // 128 KB
  ushort_t* Ks0 = (ushort_t*)smem;          // [128 keys][16 chunks] swizzled
  ushort_t* Ks1 = (ushort_t*)(smem + 8192);
  ushort_t* Vs  = (ushort_t*)(smem + 16384);// [128 d][16 key-chunks] swizzled
  uint32*   Pb  = smem + 24576;             // 8 waves x [32 rows][32 dw] group-XOR
  float*    Lred = (float*)(smem + 24576);  // epilogue alias (P dead): 256 dw
  float*    Rbuf = (float*)smem;            // epilogue alias (Ks dead): 2x16x132 dw

  const int tid = threadIdx.x;
  const int lane = tid & 63, wave = tid >> 6;
  const int quad = lane >> 4, l16 = lane & 15;
  const int qh = wave >> 1, kh = wave & 1;
  const int bid = blockIdx.x;
  const int head = ((bid & 7) << 1) + (bid >> 7);
  const int qt = (bid >> 3) & 15;           // 128-row q-tile

  const ushort_t* Kbase = Kg + (size_t)head * 128;
  const ushort_t* Vbase = Vt + (size_t)head * 128 * 2048;
  uint32* Pw = Pb + wave * 1024;

  // ---- Q -> registers (one-time scattered loads) ----
  f32x4 zero = {0.f, 0.f, 0.f, 0.f};
  short8 qr[2][4];
#pragma unroll
  for (int qg = 0; qg < 2; ++qg)
#pragma unroll
    for (int kk = 0; kk < 4; ++kk)
      qr[qg][kk] = *(const short8*)&Q[(size_t)(qt * 128 + qh * 32 + qg * 16 + l16) * 2048 +
                                      head * 128 + kk * 32 + quad * 8];

  f32x4 oacc[2][8];
#pragma unroll
  for (int qg = 0; qg < 2; ++qg)
#pragma unroll
    for (int ns = 0; ns < 8; ++ns) oacc[qg][ns] = zero;
  float l_acc[2] = {0.f, 0.f};

#define STAGE_K(KD, T)                                                           \
  _Pragma("unroll") for (int j_ = 0; j_ < 4; ++j_) {                             \
    int s_ = tid + 512 * j_; int r_ = s_ >> 4, c_ = s_ & 15;                     \
    LDS_LOAD16(Kbase + (size_t)((T) * 128 + r_) * 2048 + ((c_ ^ (r_ & 15)) * 8), \
               &(KD)[s_ * 8]);                                                   \
  }
#define STAGE_V(T)                                                               \
  _Pragma("unroll") for (int j_ = 0; j_ < 4; ++j_) {                             \
    int s_ = tid + 512 * j_; int r_ = s_ >> 4, c_ = s_ & 15;                     \
    LDS_LOAD16(Vbase + (size_t)r_ * 2048 + (T) * 128 + ((c_ ^ (r_ & 15)) * 8),   \
               &Vs[s_ * 8]);                                                     \
  }

#define ATTN_BODY(KCUR, KNXT, T, NOTLAST, VMW1)                                  \
  do {                                                                           \
    STAGE_V(T);                                                                  \
    if (NOTLAST) { STAGE_K(KNXT, (T) + 1); }                                     \
    _Pragma("unroll") for (int kg = 0; kg < 4; ++kg) {                           \
      short8 kf[4];                                                              \
      _Pragma("unroll") for (int kk = 0; kk < 4; ++kk)                           \
        kf[kk] = *(const short8*)&(KCUR)[((kh * 64 + kg * 16 + l16) * 16 +       \
                                          ((kk * 4 + quad) ^ l16)) * 8];         \
      _Pragma("unroll") for (int qg = 0; qg < 2; ++qg) {                         \
        f32x4 s = zero;                                                          \
        _Pragma("unroll") for (int kk = 0; kk < 4; ++kk)                         \
          s = __builtin_amdgcn_mfma_f32_16x16x32_bf16(kf[kk], qr[qg][kk], s, 0, 0, 0); \
        float p0 = __expf(s[0]), p1 = __expf(s[1]);                              \
        float p2 = __expf(s[2]), p3 = __expf(s[3]);                              \
        l_acc[qg] += (p0 + p1) + (p2 + p3);                                      \
        u32x2 wv; wv[0] = pk2(p0, p1); wv[1] = pk2(p2, p3);                      \
        *(u32x2*)&Pw[(qg * 16 + l16) * 32 +                                      \
                     (((kg * 2 + (quad >> 1)) ^ (l16 & 7)) << 2) +               \
                     ((quad & 1) << 1)] = wv;                                    \
      }                                                                          \
    }                                                                            \
    short8 pb[2][2];                                                             \
    _Pragma("unroll") for (int qg = 0; qg < 2; ++qg)                             \
      _Pragma("unroll") for (int ks = 0; ks < 2; ++ks)                           \
        pb[qg][ks] = *(const short8*)&Pw[(qg * 16 + l16) * 32 +                  \
                                         ((((ks << 2) + quad) ^ (l16 & 7)) << 2)]; \
    asm volatile("s_waitcnt " VMW1 ::: "memory");                                \
    __builtin_amdgcn_s_barrier();                                                \
    _Pragma("unroll") for (int ns = 0; ns < 8; ++ns)                             \
      _Pragma("unroll") for (int ks = 0; ks < 2; ++ks) {                         \
        const short8 vf = *(const short8*)&Vs[((ns * 16 + l16) * 16 +            \
                                               ((kh * 8 + ks * 4 + quad) ^ l16)) * 8]; \
        _Pragma("unroll") for (int qg = 0; qg < 2; ++qg)                         \
          oacc[qg][ns] = __builtin_amdgcn_mfma_f32_16x16x32_bf16(vf, pb[qg][ks], oacc[qg][ns], 0, 0, 0); \
      }                                                                          \
    asm volatile("s_waitcnt lgkmcnt(0)" ::: "memory");                           \
    asm volatile("s_waitcnt vmcnt(0)" ::: "memory");                             \
    __builtin_amdgcn_s_barrier();                                                \
  } while (0)

  // prologue: K(0) staged; Q loads retired by the same vmcnt(0)
  STAGE_K(Ks0, 0);
  asm volatile("s_waitcnt vmcnt(0)" ::: "memory");
  __builtin_amdgcn_s_barrier();

  for (int t2 = 0; t2 < 14; t2 += 2) {
    ATTN_BODY(Ks0, Ks1, t2 + 0, 1, "vmcnt(4)");
    ATTN_BODY(Ks1, Ks0, t2 + 1, 1, "vmcnt(4)");
  }
  ATTN_BODY(Ks0, Ks1, 14, 1, "vmcnt(4)");
  ATTN_BODY(Ks1, Ks0, 15, 0, "vmcnt(0)");   // no K prefetch; drain V fully

  // ---- reductions & epilogue (P/Ks/Vs dead; aliases safe after last barrier) ----
#pragma unroll
  for (int qg = 0; qg < 2; ++qg) {
    float l = l_acc[qg];
    l += __shfl_xor(l, 16, 64);
    l += __shfl_xor(l, 32, 64);
    l_acc[qg] = l;
  }
  if (quad == 0) {
#pragma unroll
    for (int qg = 0; qg < 2; ++qg) Lred[wave * 32 + qg * 16 + l16] = l_acc[qg];
  }

  const int tq = (tid >> 4) & 15;
  const int td = (tid & 15) * 8;
  for (int p = 0; p < 8; ++p) {             // p = (qh<<1)|qg
    __builtin_amdgcn_s_barrier();           // pass 0: Lred visible; Rbuf free
    if ((wave >> 1) == (p >> 1)) {
      const int qg = p & 1;
#pragma unroll
      for (int ns = 0; ns < 8; ++ns)
        *(f32x4*)&Rbuf[((kh * 16 + l16)) * 132 + ns * 16 + quad * 4] = oacc[qg][ns];
    }
    __builtin_amdgcn_s_barrier();
    if (tid < 256) {
      float lt = Lred[((p >> 1) * 2 + 0) * 32 + (p & 1) * 16 + tq] +
                 Lred[((p >> 1) * 2 + 1) * 32 + (p & 1) * 16 + tq];
      float inv = 1.0f / lt;
      f32x4 sA = zero, sB = zero;
#pragma unroll
      for (int k = 0; k < 2; ++k) {
        sA += *(const f32x4*)&Rbuf[(k * 16 + tq) * 132 + td];
        sB += *(const f32x4*)&Rbuf[(k * 16 + tq) * 132 + td + 4];
      }
      ushort4 o1, o2;
      o1.x = f2b(sA[0] * inv); o1.y = f2b(sA[1] * inv);
      o1.z = f2b(sA[2] * inv); o1.w = f2b(sA[3] * inv);
      o2.x = f2b(sB[0] * inv); o2.y = f2b(sB[1] * inv);
      o2.z = f2b(sB[2] * inv); o2.w = f2b(sB[3] * inv);
      size_t orow = (size_t)(qt * 128 + (p >> 1) * 32 + (p & 1) * 16 + tq) * 2048 + head * 128 + td;
      *(ushort4*)&O[orow] = o1;
      *(ushort4*)&O[orow + 4] = o2;
    }
  }
}

// ---------------- Wo GEMM-BT, split-K=2: 128x128 tile, 3-buffer BK=32 pipeline (R5) ----------------
__global__ __launch_bounds__(256, 3) void k_gemm_wo_sk(const ushort_t* __restrict__ A,
                                                       const ushort_t* __restrict__ B,
                                                       float* __restrict__ P) {
  __shared__ ushort_t As[3][128 * 32];
  __shared__ ushort_t Bs[3][128 * 32];
  const int tid = threadIdx.x;
  const int lane = tid & 63, wave = tid >> 6;
  const int quad = lane >> 4, l16 = lane & 15;
  const int wm = wave >> 1, wn = wave & 1;
  const size_t row0 = (size_t)blockIdx.y * 128, col0 = (size_t)blockIdx.x * 128;
  const int k0 = blockIdx.z * 1024;
  float* Pz = P + (size_t)blockIdx.z * E;
  const ushort_t* Ak = A + k0;
  const ushort_t* Bk = B + k0;

  f32x4 zero = {0.f, 0.f, 0.f, 0.f};
  f32x4 acc[4][4];
#pragma unroll
  for (int i = 0; i < 4; ++i)
#pragma unroll
    for (int j = 0; j < 4; ++j) acc[i][j] = zero;

#define WO_FRAGS(CUR)                                                           \
    short8 a_[4], b_[4];                                                        \
    _Pragma("unroll") for (int i_ = 0; i_ < 4; ++i_) {                          \
      int ra_ = wm * 64 + i_ * 16 + l16;                                        \
      a_[i_] = *(const short8*)&As[CUR][(ra_ * 4 + (quad ^ SWZ3(ra_))) * 8];    \
    }                                                                           \
    _Pragma("unroll") for (int j_ = 0; j_ < 4; ++j_) {                          \
      int rb_ = wn * 64 + j_ * 16 + l16;                                        \
      b_[j_] = *(const short8*)&Bs[CUR][(rb_ * 4 + (quad ^ SWZ3(rb_))) * 8];    \
    }                                                                           \
    _Pragma("unroll") for (int i_ = 0; i_ < 4; ++i_)                            \
      _Pragma("unroll") for (int j_ = 0; j_ < 4; ++j_)                          \
        acc[i_][j_] = __builtin_amdgcn_mfma_f32_16x16x32_bf16(a_[i_], b_[j_], acc[i_][j_], 0, 0, 0);

#define WO_BODY(T, CUR, STG, SEN, VM)                                           \
  do {                                                                          \
    if (SEN) STG32(Ak, Bk, As[STG], Bs[STG], (T) + 2);                          \
    WO_FRAGS(CUR)                                                               \
    asm volatile("s_waitcnt " VM ::: "memory");                                 \
    __builtin_amdgcn_s_barrier();                                               \
  } while (0)

  STG32(Ak, Bk, As[0], Bs[0], 0);
  STG32(Ak, Bk, As[1], Bs[1], 1);
  asm volatile("s_waitcnt vmcnt(4)" ::: "memory");
  __builtin_amdgcn_s_barrier();

  for (int tt = 0; tt < 27; tt += 3) {
    WO_BODY(tt + 0, 0, 2, 1, "vmcnt(4)");
    WO_BODY(tt + 1, 1, 0, 1, "vmcnt(4)");
    WO_BODY(tt + 2, 2, 1, 1, "vmcnt(4)");
  }
  WO_BODY(27, 0, 2, 1, "vmcnt(4)");
  WO_BODY(28, 1, 0, 1, "vmcnt(4)");
  WO_BODY(29, 2, 1, 1, "vmcnt(4)");    // stages tile 31 into buf 1
  WO_BODY(30, 0, 2, 0, "vmcnt(0)");    // no stage left; retire tile 31
  { WO_FRAGS(1) }                      // t=31, no wait/barrier needed

#pragma unroll
  for (int i = 0; i < 4; ++i)
#pragma unroll
    for (int j = 0; j < 4; ++j)
#pragma unroll
      for (int r = 0; r < 4; ++r) {
        size_t row = row0 + wm * 64 + i * 16 + quad * 4 + r;
        size_t col = col0 + wn * 64 + j * 16 + l16;
        Pz[row * 2048 + col] = acc[i][j][r];
      }
}

// ---------------- split-K reduce: out = P0 + P1 (fp32) ----------------
__global__ __launch_bounds__(256) void k_red(const float* __restrict__ P, float* __restrict__ out) {
  size_t i = ((size_t)blockIdx.x * 256 + threadIdx.x) * 4;
  f32x4 a = *(const f32x4*)(P + i);
  f32x4 b = *(const f32x4*)(P + E + i);
  *(f32x4*)(out + i) = a + b;
}

extern "C" void kernel_launch(void* const* d_in, const int* in_sizes, int n_in,
                              void* d_out, int out_size, void* d_ws, size_t ws_size,
                              hipStream_t stream) {
  const float* X  = (const float*)d_in[0];
  const float* wq = (const float*)d_in[1];
  const float* wk = (const float*)d_in[2];
  const float* wv = (const float*)d_in[3];
  const float* wo = (const float*)d_in[4];
  const int*  pos = (const int*)d_in[5];
  float* out = (float*)d_out;

  if (ws_size < 9 * E * sizeof(ushort_t)) return;  // need 72 MB scratch

  ushort_t* Xb  = (ushort_t*)d_ws;
  ushort_t* Wqb = Xb + E;
  ushort_t* Wkb = Xb + 2 * E;
  ushort_t* Wvb = Xb + 3 * E;
  ushort_t* Wob = Xb + 4 * E;
  ushort_t* Qm  = Xb + 5 * E;
  ushort_t* Km  = Xb + 6 * E;
  ushort_t* Vtm = Xb + 7 * E;
  ushort_t* Om  = Xb + 8 * E;
  // After k_attn, Xb..Wvb (4E ushorts = 32 MB) are dead: reuse as 2x fp32 partial planes.
  float* Pf = (float*)Xb;   // P0 = [0,E) floats, P1 = [E,2E) floats

  dim3 b256(256);
  k_cvt5<<<dim3(4096, 5), b256, 0, stream>>>(X, wq, wk, wv, wo, Xb);
  k_gemm_qkv<<<dim3(16, 16, 3), b256, 0, stream>>>(Xb, Wqb, Wkb, Wvb, Qm, Km, Vtm, pos);
  k_attn<<<256, dim3(512), 0, stream>>>(Qm, Km, Vtm, Om);
  k_gemm_wo_sk<<<dim3(16, 16, 2), b256, 0, stream>>>(Om, Wob, Pf);
  k_red<<<4096, b256, 0, stream>>>(Pf, out);
}

// Round 9
// 266.651 us; speedup vs baseline: 1.2039x; 1.0000x over previous
//
#include <hip/hip_runtime.h>

typedef unsigned short ushort_t;
typedef unsigned int uint32;
typedef __attribute__((ext_vector_type(8))) short short8;
typedef __attribute__((ext_vector_type(4))) float f32x4;
typedef __attribute__((ext_vector_type(2))) uint32 u32x2;

#define LDS_LOAD16(gptr, lptr)                                                             \
  __builtin_amdgcn_global_load_lds((const __attribute__((address_space(1))) uint32*)(gptr),\
                                   (__attribute__((address_space(3))) uint32*)(lptr),      \
                                   16, 0, 0)

__device__ __forceinline__ ushort_t f2b(float f) {
  uint32 u = __builtin_bit_cast(uint32, f);
  u += 0x7fffu + ((u >> 16) & 1u);   // RNE
  return (ushort_t)(u >> 16);
}
__device__ __forceinline__ uint32 pk2(float a, float b) {
  return (uint32)f2b(a) | ((uint32)f2b(b) << 16);
}

constexpr size_t E = (size_t)2048 * 2048;

// ---------------- fused fp32 -> bf16 convert (all 5 tensors) ----------------
__global__ __launch_bounds__(256) void k_cvt5(const float* __restrict__ a0, const float* __restrict__ a1,
                                              const float* __restrict__ a2, const float* __restrict__ a3,
                                              const float* __restrict__ a4, ushort_t* __restrict__ out) {
  const float* srcs[5] = {a0, a1, a2, a3, a4};
  const float* s = srcs[blockIdx.y];
  size_t i = ((size_t)blockIdx.x * 256 + threadIdx.x) * 4;
  float4 v = *(const float4*)(s + i);
  ushort4 o;
  o.x = f2b(v.x); o.y = f2b(v.y); o.z = f2b(v.z); o.w = f2b(v.w);
  *(ushort4*)(out + (size_t)blockIdx.y * E + i) = o;
}

// ===================== 3-buffer BK=32 rotating GEMM pipeline (R5-verified, 70us) =====================
#define SWZ3(r) (((r) >> 1) & 3)

#define STG32(srcA, srcB, dA, dB, ktile)                                        \
  do {                                                                          \
    const int koff_ = (ktile) * 32;                                             \
    _Pragma("unroll") for (int j2_ = 0; j2_ < 2; ++j2_) {                       \
      int c_ = tid + 256 * j2_;                                                 \
      int r_ = c_ >> 2, p_ = c_ & 3;                                            \
      int sc_ = (p_ ^ SWZ3(r_)) * 8;                                            \
      LDS_LOAD16((srcA) + (row0 + r_) * 2048 + koff_ + sc_, &(dA)[c_ * 8]);     \
      LDS_LOAD16((srcB) + (col0 + r_) * 2048 + koff_ + sc_, &(dB)[c_ * 8]);     \
    }                                                                           \
  } while (0)

// ---------------- fused QKV GEMM-BT, fused RoPE epilogue ----------------
__global__ __launch_bounds__(256, 3) void k_gemm_qkv(const ushort_t* __restrict__ A,
                                                     const ushort_t* __restrict__ B0,
                                                     const ushort_t* __restrict__ B1,
                                                     const ushort_t* __restrict__ B2,
                                                     ushort_t* __restrict__ Qm,
                                                     ushort_t* __restrict__ Km,
                                                     ushort_t* __restrict__ Vt,
                                                     const int* __restrict__ pos) {
  __shared__ ushort_t As[3][128 * 32];
  __shared__ ushort_t Bs[3][128 * 32];
  const int tid = threadIdx.x;
  const int lane = tid & 63, wave = tid >> 6;
  const int quad = lane >> 4, l16 = lane & 15;
  const int wm = wave >> 1, wn = wave & 1;
  const int z = blockIdx.z;
  const ushort_t* Bp = (z == 0) ? B0 : (z == 1) ? B1 : B2;
  const size_t row0 = (size_t)blockIdx.y * 128, col0 = (size_t)blockIdx.x * 128;

  int g[4];
#pragma unroll
  for (int j = 0; j < 4; ++j) g[j] = (j & 1) + ((j >> 1) << 2) + wn * 2;  // {0,1,4,5}/{2,3,6,7}

  f32x4 zero = {0.f, 0.f, 0.f, 0.f};
  f32x4 acc[4][4];
#pragma unroll
  for (int i = 0; i < 4; ++i)
#pragma unroll
    for (int j = 0; j < 4; ++j) acc[i][j] = zero;

#define QKV_FRAGS(CUR)                                                          \
    short8 a_[4], b_[4];                                                        \
    _Pragma("unroll") for (int i_ = 0; i_ < 4; ++i_) {                          \
      int ra_ = wm * 64 + i_ * 16 + l16;                                        \
      a_[i_] = *(const short8*)&As[CUR][(ra_ * 4 + (quad ^ SWZ3(ra_))) * 8];    \
    }                                                                           \
    _Pragma("unroll") for (int j_ = 0; j_ < 4; ++j_) {                          \
      int rb_ = g[j_] * 16 + l16;                                               \
      b_[j_] = *(const short8*)&Bs[CUR][(rb_ * 4 + (quad ^ SWZ3(rb_))) * 8];    \
    }                                                                           \
    _Pragma("unroll") for (int i_ = 0; i_ < 4; ++i_)                            \
      _Pragma("unroll") for (int j_ = 0; j_ < 4; ++j_)                          \
        acc[i_][j_] = __builtin_amdgcn_mfma_f32_16x16x32_bf16(a_[i_], b_[j_], acc[i_][j_], 0, 0, 0);

#define QKV_BODY(T, CUR, STG, SEN, VM)                                          \
  do {                                                                          \
    if (SEN) STG32(A, Bp, As[STG], Bs[STG], (T) + 2);                           \
    QKV_FRAGS(CUR)                                                              \
    asm volatile("s_waitcnt " VM ::: "memory");                                 \
    __builtin_amdgcn_s_barrier();                                               \
  } while (0)

  STG32(A, Bp, As[0], Bs[0], 0);
  STG32(A, Bp, As[1], Bs[1], 1);
  asm volatile("s_waitcnt vmcnt(4)" ::: "memory");
  __builtin_amdgcn_s_barrier();

  for (int tt = 0; tt < 60; tt += 3) {
    QKV_BODY(tt + 0, 0, 2, 1, "vmcnt(4)");
    QKV_BODY(tt + 1, 1, 0, 1, "vmcnt(4)");
    QKV_BODY(tt + 2, 2, 1, 1, "vmcnt(4)");
  }
  QKV_BODY(60, 0, 2, 1, "vmcnt(4)");
  QKV_BODY(61, 1, 0, 1, "vmcnt(4)");   // stages tile 63 into buf 0
  QKV_BODY(62, 2, 1, 0, "vmcnt(0)");   // no stage left; retire tile 63
  { QKV_FRAGS(0) }                     // t=63, no wait/barrier needed

  if (z < 2) {
    ushort_t* C = z ? Km : Qm;
    const float mul = z ? 1.0f : 0.08838834764831845f;  // fold 1/sqrt(128) into Q
#pragma unroll
    for (int i = 0; i < 4; ++i)
#pragma unroll
      for (int r = 0; r < 4; ++r) {
        size_t row = row0 + wm * 64 + i * 16 + quad * 4 + r;
        float pt = (float)pos[row];
        size_t rowoff = row * 2048 + col0;
#pragma unroll
        for (int j = 0; j < 2; ++j) {
          int f = g[j] * 16 + l16;   // f in [0,64)
          float ang = pt * __expf(-0.14391156831212787f * (float)f);
          float sn, cs;
          __sincosf(ang, &sn, &cs);
          cs *= mul; sn *= mul;
          float q0 = acc[i][j][r], q1 = acc[i][j + 2][r];
          C[rowoff + f]      = f2b(q0 * cs - q1 * sn);
          C[rowoff + f + 64] = f2b(q1 * cs + q0 * sn);
        }
      }
  } else {
#pragma unroll
    for (int i = 0; i < 4; ++i)
#pragma unroll
      for (int j = 0; j < 4; ++j) {
        size_t col = col0 + g[j] * 16 + l16;
        size_t rowb = row0 + wm * 64 + i * 16 + quad * 4;
        ushort4 ov;
        ov.x = f2b(acc[i][j][0]); ov.y = f2b(acc[i][j][1]);
        ov.z = f2b(acc[i][j][2]); ov.w = f2b(acc[i][j][3]);
        *(ushort4*)&Vt[col * 2048 + rowb] = ov;
      }
  }
}

// ---------------- flash attention v9: v8 + K AND V double-buffered, counted vmcnt, no drains ----------------
// Grid 256 = 1 block/CU. v8's per-body vmcnt(0)+lgkmcnt(0) drain serialized the whole CU
// (1 block/CU -> nothing to hide behind). v9: stage K(t+1)+V(t+1) at body top (8 vmem/thr),
// retire PREVIOUS body's tiles with counted vmcnt(8)+barrier, compute on current buffers,
// one closing barrier. Steady state never drains. LDS = Ks 2x32K + Vs 2x32K + P 32K =
// 160 KB exactly (full CU pool; HK/AITER attn run 160KB workgroups on gfx950 — m243).
__global__ __launch_bounds__(512, 2) void k_attn(const ushort_t* __restrict__ Q,
                                                 const ushort_t* __restrict__ Kg,
                                                 const ushort_t* __restrict__ Vt,
                                                 ushort_t* __restrict__ O) {
  __shared__ uint32 smem[40960];            // 160 KB exactly
  ushort_t* Ks0 = (ushort_t*)smem;          // [128 keys][16 chunks] swizzled, 32KB
  ushort_t* Ks1 = (ushort_t*)(smem + 8192);
  ushort_t* Vs0 = (ushort_t*)(smem + 16384);// [128 d][16 key-chunks] swizzled, 32KB
  ushort_t* Vs1 = (ushort_t*)(smem + 24576);
  uint32*   Pb  = smem + 32768;             // 8 waves x [32 rows][32 dw] group-XOR, 32KB
  float*    Lred = (float*)(smem + 32768);  // epilogue alias (P dead): 256 dw
  float*    Rbuf = (float*)smem;            // epilogue alias (Ks dead): 2x16x132 dw

  const int tid = threadIdx.x;
  const int lane = tid & 63, wave = tid >> 6;
  const int quad = lane >> 4, l16 = lane & 15;
  const int qh = wave >> 1, kh = wave & 1;
  const int bid = blockIdx.x;
  const int head = ((bid & 7) << 1) + (bid >> 7);
  const int qt = (bid >> 3) & 15;           // 128-row q-tile

  const ushort_t* Kbase = Kg + (size_t)head * 128;
  const ushort_t* Vbase = Vt + (size_t)head * 128 * 2048;
  uint32* Pw = Pb + wave * 1024;

  // ---- Q -> registers (one-time scattered loads) ----
  f32x4 zero = {0.f, 0.f, 0.f, 0.f};
  short8 qr[2][4];
#pragma unroll
  for (int qg = 0; qg < 2; ++qg)
#pragma unroll
    for (int kk = 0; kk < 4; ++kk)
      qr[qg][kk] = *(const short8*)&Q[(size_t)(qt * 128 + qh * 32 + qg * 16 + l16) * 2048 +
                                      head * 128 + kk * 32 + quad * 8];

  f32x4 oacc[2][8];
#pragma unroll
  for (int qg = 0; qg < 2; ++qg)
#pragma unroll
    for (int ns = 0; ns < 8; ++ns) oacc[qg][ns] = zero;
  float l_acc[2] = {0.f, 0.f};

#define STAGE_K(KD, T)                                                           \
  _Pragma("unroll") for (int j_ = 0; j_ < 4; ++j_) {                             \
    int s_ = tid + 512 * j_; int r_ = s_ >> 4, c_ = s_ & 15;                     \
    LDS_LOAD16(Kbase + (size_t)((T) * 128 + r_) * 2048 + ((c_ ^ (r_ & 15)) * 8), \
               &(KD)[s_ * 8]);                                                   \
  }
#define STAGE_V(VD, T)                                                           \
  _Pragma("unroll") for (int j_ = 0; j_ < 4; ++j_) {                             \
    int s_ = tid + 512 * j_; int r_ = s_ >> 4, c_ = s_ & 15;                     \
    LDS_LOAD16(Vbase + (size_t)r_ * 2048 + (T) * 128 + ((c_ ^ (r_ & 15)) * 8),   \
               &(VD)[s_ * 8]);                                                   \
  }

// body t: stage K/V(t+1) -> alt buffers; vmcnt(8) retires K/V(t) (staged last body),
// keeps this body's 8 in flight; barrier; QK/P/PV on current buffers; barrier.
// Closing barrier makes next body's stage (into the buffers just read) WAR-safe.
#define ATTN_BODY(KCUR, KNXT, VCUR, VNXT, T, NOTLAST, VMW)                       \
  do {                                                                           \
    if (NOTLAST) { STAGE_K(KNXT, (T) + 1); STAGE_V(VNXT, (T) + 1); }             \
    asm volatile("s_waitcnt " VMW ::: "memory");                                 \
    __builtin_amdgcn_s_barrier();                                                \
    asm volatile("" ::: "memory");                                               \
    _Pragma("unroll") for (int kg = 0; kg < 4; ++kg) {                           \
      short8 kf[4];                                                              \
      _Pragma("unroll") for (int kk = 0; kk < 4; ++kk)                           \
        kf[kk] = *(const short8*)&(KCUR)[((kh * 64 + kg * 16 + l16) * 16 +       \
                                          ((kk * 4 + quad) ^ l16)) * 8];         \
      _Pragma("unroll") for (int qg = 0; qg < 2; ++qg) {                         \
        f32x4 s = zero;                                                          \
        _Pragma("unroll") for (int kk = 0; kk < 4; ++kk)                         \
          s = __builtin_amdgcn_mfma_f32_16x16x32_bf16(kf[kk], qr[qg][kk], s, 0, 0, 0); \
        float p0 = __expf(s[0]), p1 = __expf(s[1]);                              \
        float p2 = __expf(s[2]), p3 = __expf(s[3]);                              \
        l_acc[qg] += (p0 + p1) + (p2 + p3);                                      \
        u32x2 wv; wv[0] = pk2(p0, p1); wv[1] = pk2(p2, p3);                      \
        *(u32x2*)&Pw[(qg * 16 + l16) * 32 +                                      \
                     (((kg * 2 + (quad >> 1)) ^ (l16 & 7)) << 2) +               \
                     ((quad & 1) << 1)] = wv;                                    \
      }                                                                          \
    }                                                                            \
    short8 pb[2][2];                                                             \
    _Pragma("unroll") for (int qg = 0; qg < 2; ++qg)                             \
      _Pragma("unroll") for (int ks = 0; ks < 2; ++ks)                           \
        pb[qg][ks] = *(const short8*)&Pw[(qg * 16 + l16) * 32 +                  \
                                         ((((ks << 2) + quad) ^ (l16 & 7)) << 2)]; \
    _Pragma("unroll") for (int ns = 0; ns < 8; ++ns)                             \
      _Pragma("unroll") for (int ks = 0; ks < 2; ++ks) {                         \
        const short8 vf = *(const short8*)&(VCUR)[((ns * 16 + l16) * 16 +        \
                                               ((kh * 8 + ks * 4 + quad) ^ l16)) * 8]; \
        _Pragma("unroll") for (int qg = 0; qg < 2; ++qg)                         \
          oacc[qg][ns] = __builtin_amdgcn_mfma_f32_16x16x32_bf16(vf, pb[qg][ks], oacc[qg][ns], 0, 0, 0); \
      }                                                                          \
    asm volatile("" ::: "memory");                                               \
    __builtin_amdgcn_s_barrier();                                                \
    asm volatile("" ::: "memory");                                               \
  } while (0)

  // prologue: K(0),V(0) staged; Q reg loads retired by the same vmcnt(0)
  STAGE_K(Ks0, 0);
  STAGE_V(Vs0, 0);
  asm volatile("s_waitcnt vmcnt(0)" ::: "memory");
  __builtin_amdgcn_s_barrier();
  asm volatile("" ::: "memory");

  for (int t2 = 0; t2 < 14; t2 += 2) {
    ATTN_BODY(Ks0, Ks1, Vs0, Vs1, t2 + 0, 1, "vmcnt(8)");
    ATTN_BODY(Ks1, Ks0, Vs1, Vs0, t2 + 1, 1, "vmcnt(8)");
  }
  ATTN_BODY(Ks0, Ks1, Vs0, Vs1, 14, 1, "vmcnt(8)");
  ATTN_BODY(Ks1, Ks0, Vs1, Vs0, 15, 0, "vmcnt(0)");  // no stage; retire K/V(15)

  // ---- reductions & epilogue (P/Ks/Vs dead; aliases safe after last barrier) ----
#pragma unroll
  for (int qg = 0; qg < 2; ++qg) {
    float l = l_acc[qg];
    l += __shfl_xor(l, 16, 64);
    l += __shfl_xor(l, 32, 64);
    l_acc[qg] = l;
  }
  if (quad == 0) {
#pragma unroll
    for (int qg = 0; qg < 2; ++qg) Lred[wave * 32 + qg * 16 + l16] = l_acc[qg];
  }

  const int tq = (tid >> 4) & 15;
  const int td = (tid & 15) * 8;
  for (int p = 0; p < 8; ++p) {             // p = (qh<<1)|qg
    __builtin_amdgcn_s_barrier();           // pass 0: Lred visible; Rbuf free
    if ((wave >> 1) == (p >> 1)) {
      const int qg = p & 1;
#pragma unroll
      for (int ns = 0; ns < 8; ++ns)
        *(f32x4*)&Rbuf[((kh * 16 + l16)) * 132 + ns * 16 + quad * 4] = oacc[qg][ns];
    }
    __builtin_amdgcn_s_barrier();
    if (tid < 256) {
      float lt = Lred[((p >> 1) * 2 + 0) * 32 + (p & 1) * 16 + tq] +
                 Lred[((p >> 1) * 2 + 1) * 32 + (p & 1) * 16 + tq];
      float inv = 1.0f / lt;
      f32x4 sA = zero, sB = zero;
#pragma unroll
      for (int k = 0; k < 2; ++k) {
        sA += *(const f32x4*)&Rbuf[(k * 16 + tq) * 132 + td];
        sB += *(const f32x4*)&Rbuf[(k * 16 + tq) * 132 + td + 4];
      }
      ushort4 o1, o2;
      o1.x = f2b(sA[0] * inv); o1.y = f2b(sA[1] * inv);
      o1.z = f2b(sA[2] * inv); o1.w = f2b(sA[3] * inv);
      o2.x = f2b(sB[0] * inv); o2.y = f2b(sB[1] * inv);
      o2.z = f2b(sB[2] * inv); o2.w = f2b(sB[3] * inv);
      size_t orow = (size_t)(qt * 128 + (p >> 1) * 32 + (p & 1) * 16 + tq) * 2048 + head * 128 + td;
      *(ushort4*)&O[orow] = o1;
      *(ushort4*)&O[orow + 4] = o2;
    }
  }
}

// ---------------- Wo GEMM-BT, split-K=2: 128x128 tile, 3-buffer BK=32 pipeline (R5) ----------------
__global__ __launch_bounds__(256, 3) void k_gemm_wo_sk(const ushort_t* __restrict__ A,
                                                       const ushort_t* __restrict__ B,
                                                       float* __restrict__ P) {
  __shared__ ushort_t As[3][128 * 32];
  __shared__ ushort_t Bs[3][128 * 32];
  const int tid = threadIdx.x;
  const int lane = tid & 63, wave = tid >> 6;
  const int quad = lane >> 4, l16 = lane & 15;
  const int wm = wave >> 1, wn = wave & 1;
  const size_t row0 = (size_t)blockIdx.y * 128, col0 = (size_t)blockIdx.x * 128;
  const int k0 = blockIdx.z * 1024;
  float* Pz = P + (size_t)blockIdx.z * E;
  const ushort_t* Ak = A + k0;
  const ushort_t* Bk = B + k0;

  f32x4 zero = {0.f, 0.f, 0.f, 0.f};
  f32x4 acc[4][4];
#pragma unroll
  for (int i = 0; i < 4; ++i)
#pragma unroll
    for (int j = 0; j < 4; ++j) acc[i][j] = zero;

#define WO_FRAGS(CUR)                                                           \
    short8 a_[4], b_[4];                                                        \
    _Pragma("unroll") for (int i_ = 0; i_ < 4; ++i_) {                          \
      int ra_ = wm * 64 + i_ * 16 + l16;                                        \
      a_[i_] = *(const short8*)&As[CUR][(ra_ * 4 + (quad ^ SWZ3(ra_))) * 8];    \
    }                                                                           \
    _Pragma("unroll") for (int j_ = 0; j_ < 4; ++j_) {                          \
      int rb_ = wn * 64 + j_ * 16 + l16;                                        \
      b_[j_] = *(const short8*)&Bs[CUR][(rb_ * 4 + (quad ^ SWZ3(rb_))) * 8];    \
    }                                                                           \
    _Pragma("unroll") for (int i_ = 0; i_ < 4; ++i_)                            \
      _Pragma("unroll") for (int j_ = 0; j_ < 4; ++j_)                          \
        acc[i_][j_] = __builtin_amdgcn_mfma_f32_16x16x32_bf16(a_[i_], b_[j_], acc[i_][j_], 0, 0, 0);

#define WO_BODY(T, CUR, STG, SEN, VM)                                           \
  do {                                                                          \
    if (SEN) STG32(Ak, Bk, As[STG], Bs[STG], (T) + 2);                          \
    WO_FRAGS(CUR)                                                               \
    asm volatile("s_waitcnt " VM ::: "memory");                                 \
    __builtin_amdgcn_s_barrier();                                               \
  } while (0)

  STG32(Ak, Bk, As[0], Bs[0], 0);
  STG32(Ak, Bk, As[1], Bs[1], 1);
  asm volatile("s_waitcnt vmcnt(4)" ::: "memory");
  __builtin_amdgcn_s_barrier();

  for (int tt = 0; tt < 27; tt += 3) {
    WO_BODY(tt + 0, 0, 2, 1, "vmcnt(4)");
    WO_BODY(tt + 1, 1, 0, 1, "vmcnt(4)");
    WO_BODY(tt + 2, 2, 1, 1, "vmcnt(4)");
  }
  WO_BODY(27, 0, 2, 1, "vmcnt(4)");
  WO_BODY(28, 1, 0, 1, "vmcnt(4)");
  WO_BODY(29, 2, 1, 1, "vmcnt(4)");    // stages tile 31 into buf 1
  WO_BODY(30, 0, 2, 0, "vmcnt(0)");    // no stage left; retire tile 31
  { WO_FRAGS(1) }                      // t=31, no wait/barrier needed

#pragma unroll
  for (int i = 0; i < 4; ++i)
#pragma unroll
    for (int j = 0; j < 4; ++j)
#pragma unroll
      for (int r = 0; r < 4; ++r) {
        size_t row = row0 + wm * 64 + i * 16 + quad * 4 + r;
        size_t col = col0 + wn * 64 + j * 16 + l16;
        Pz[row * 2048 + col] = acc[i][j][r];
      }
}

// ---------------- split-K reduce: out = P0 + P1 (fp32) ----------------
__global__ __launch_bounds__(256) void k_red(const float* __restrict__ P, float* __restrict__ out) {
  size_t i = ((size_t)blockIdx.x * 256 + threadIdx.x) * 4;
  f32x4 a = *(const f32x4*)(P + i);
  f32x4 b = *(const f32x4*)(P + E + i);
  *(f32x4*)(out + i) = a + b;
}

extern "C" void kernel_launch(void* const* d_in, const int* in_sizes, int n_in,
                              void* d_out, int out_size, void* d_ws, size_t ws_size,
                              hipStream_t stream) {
  const float* X  = (const float*)d_in[0];
  const float* wq = (const float*)d_in[1];
  const float* wk = (const float*)d_in[2];
  const float* wv = (const float*)d_in[3];
  const float* wo = (const float*)d_in[4];
  const int*  pos = (const int*)d_in[5];
  float* out = (float*)d_out;

  if (ws_size < 9 * E * sizeof(ushort_t)) return;  // need 72 MB scratch

  ushort_t* Xb  = (ushort_t*)d_ws;
  ushort_t* Wqb = Xb + E;
  ushort_t* Wkb = Xb + 2 * E;
  ushort_t* Wvb = Xb + 3 * E;
  ushort_t* Wob = Xb + 4 * E;
  ushort_t* Qm  = Xb + 5 * E;
  ushort_t* Km  = Xb + 6 * E;
  ushort_t* Vtm = Xb + 7 * E;
  ushort_t* Om  = Xb + 8 * E;
  // After k_attn, Xb..Wvb (4E ushorts = 32 MB) are dead: reuse as 2x fp32 partial planes.
  float* Pf = (float*)Xb;   // P0 = [0,E) floats, P1 = [E,2E) floats

  dim3 b256(256);
  k_cvt5<<<dim3(4096, 5), b256, 0, stream>>>(X, wq, wk, wv, wo, Xb);
  k_gemm_qkv<<<dim3(16, 16, 3), b256, 0, stream>>>(Xb, Wqb, Wkb, Wvb, Qm, Km, Vtm, pos);
  k_attn<<<256, dim3(512), 0, stream>>>(Qm, Km, Vtm, Om);
  k_gemm_wo_sk<<<dim3(16, 16, 2), b256, 0, stream>>>(Om, Wob, Pf);
  k_red<<<4096, b256, 0, stream>>>(Pf, out);
}